// Round 3
// baseline (3004.991 us; speedup 1.0000x reference)
//
#include <hip/hip_runtime.h>
#include <hip/hip_bf16.h>

// SplineConv, K=2 degree-1 B-spline, 1-D pseudo-coords.
// out[n] = relu( mean_{e->n}( (1-v)x_src@W0 + v x_src@W1 ) + x[n]@root + bias )
//   = relu( (S/deg)@W0 + (A1/deg)@(W1-W0) + x@root + bias )
// where S[n] = sum_{e->n} x[src_e], A1[n] = sum_{e->n} v_e * x[src_e].
//
// R2 result: atomic scatter = 284G f32 atomics/s (TCC atomic ALU saturated).
// R3: counting-sort edges into per-dst buckets (1.2M int atomics only), then
// register-accumulating gather (no f32 atomics), then 2-node/thread GEMM.

#define CH 64
#define CAP 64  // bucket capacity; deg ~ Poisson(12), P(deg>64) ~ 1e-23

// ---------- main path ----------

__global__ __launch_bounds__(256) void spline_fill(
    const int* __restrict__ ei, const float* __restrict__ attr,
    int* __restrict__ cnt, int2* __restrict__ bucket, int E) {
  int e = blockIdx.x * 256 + threadIdx.x;
  if (e >= E) return;
  int src = ei[e];
  int dst = ei[E + e];
  float v = attr[e];
  int pos = atomicAdd(&cnt[dst], 1);
  if (pos < CAP) bucket[(size_t)dst * CAP + pos] = make_int2(src, __float_as_int(v));
}

__global__ __launch_bounds__(256) void spline_gather(
    const float* __restrict__ x, const int* __restrict__ cnt,
    const int2* __restrict__ bucket, float* __restrict__ S,
    float* __restrict__ A1, float* __restrict__ degf, int n) {
  int node = blockIdx.x * 4 + (threadIdx.x >> 6);
  int lane = threadIdx.x & 63;
  if (node >= n) return;
  int ctrue = cnt[node];
  int c = ctrue > CAP ? CAP : ctrue;
  int2 ent = make_int2(0, 0);
  if (lane < c) ent = bucket[(size_t)node * CAP + lane];
  float s = 0.0f, a = 0.0f;
  for (int j = 0; j < c; ++j) {
    int srcj = __shfl(ent.x, j);
    float vj = __int_as_float(__shfl(ent.y, j));
    float xv = x[(size_t)srcj * CH + lane];  // coalesced 256B gather, L2/L3-resident
    s += xv;
    a = fmaf(vj, xv, a);
  }
  S[(size_t)node * CH + lane] = s;
  A1[(size_t)node * CH + lane] = a;
  if (lane == 0) degf[node] = (float)ctrue;
}

// ---------- fallback scatter (R2 path, if ws too small) ----------

__global__ __launch_bounds__(256) void spline_scatter(
    const float* __restrict__ x, const int* __restrict__ ei,
    const float* __restrict__ attr, float* __restrict__ S,
    float* __restrict__ A1, float* __restrict__ degf, int E) {
  int w = (int)((blockIdx.x * 4) + (threadIdx.x >> 6));
  int lane = threadIdx.x & 63;
  if (w >= E) return;
  int src = ei[w];
  int dst = ei[E + w];
  float v = attr[w];
  float xv = x[(size_t)src * CH + lane];
  atomicAdd(&S[(size_t)dst * CH + lane], xv);
  atomicAdd(&A1[(size_t)dst * CH + lane], v * xv);
  if (lane == 0) atomicAdd(&degf[dst], 1.0f);
}

// ---------- fused K=192 GEMM, 2 nodes per thread ----------

__device__ __forceinline__ void accum2(
    float acc0[CH], float acc1[CH],
    const float4* __restrict__ p0, const float4* __restrict__ p1,
    float s0, float s1, const float* __restrict__ Mbase, bool v0, bool v1) {
#pragma unroll
  for (int i4 = 0; i4 < 16; ++i4) {
    float4 a4 = v0 ? p0[i4] : make_float4(0.f, 0.f, 0.f, 0.f);
    float4 b4 = v1 ? p1[i4] : make_float4(0.f, 0.f, 0.f, 0.f);
    float av[4] = {a4.x * s0, a4.y * s0, a4.z * s0, a4.w * s0};
    float bv[4] = {b4.x * s1, b4.y * s1, b4.z * s1, b4.w * s1};
#pragma unroll
    for (int j = 0; j < 4; ++j) {
      const float4* Mr = (const float4*)(Mbase + (i4 * 4 + j) * CH);
#pragma unroll
      for (int o4 = 0; o4 < 16; ++o4) {
        float4 m = Mr[o4];  // LDS broadcast, shared by both nodes
        acc0[o4 * 4 + 0] = fmaf(av[j], m.x, acc0[o4 * 4 + 0]);
        acc0[o4 * 4 + 1] = fmaf(av[j], m.y, acc0[o4 * 4 + 1]);
        acc0[o4 * 4 + 2] = fmaf(av[j], m.z, acc0[o4 * 4 + 2]);
        acc0[o4 * 4 + 3] = fmaf(av[j], m.w, acc0[o4 * 4 + 3]);
        acc1[o4 * 4 + 0] = fmaf(bv[j], m.x, acc1[o4 * 4 + 0]);
        acc1[o4 * 4 + 1] = fmaf(bv[j], m.y, acc1[o4 * 4 + 1]);
        acc1[o4 * 4 + 2] = fmaf(bv[j], m.z, acc1[o4 * 4 + 2]);
        acc1[o4 * 4 + 3] = fmaf(bv[j], m.w, acc1[o4 * 4 + 3]);
      }
    }
  }
}

__global__ __launch_bounds__(256) void spline_gemm2(
    const float* __restrict__ S, const float* __restrict__ A1,
    const float* __restrict__ degf, const float* __restrict__ x,
    const float* __restrict__ W, const float* __restrict__ root,
    const float* __restrict__ bias, float* __restrict__ out, int n) {
  __shared__ float M[192 * CH];  // rows 0..63: W0; 64..127: W1-W0; 128..191: root
  __shared__ float bs[CH];
  int t = threadIdx.x;
  for (int idx = t; idx < 64 * 64; idx += 256) {
    int i = idx >> 6, o = idx & 63;
    float w0 = W[i * 64 + o];
    float w1 = W[4096 + i * 64 + o];
    M[i * 64 + o] = w0;
    M[(64 + i) * 64 + o] = w1 - w0;
    M[(128 + i) * 64 + o] = root[i * 64 + o];
  }
  if (t < 64) bs[t] = bias[t];
  __syncthreads();

  int node0 = blockIdx.x * 512 + t;
  int node1 = node0 + 256;
  bool v0 = node0 < n, v1 = node1 < n;
  if (!v0) return;  // t ordered: if node0 OOB, node1 also OOB

  float acc0[CH], acc1[CH];
#pragma unroll
  for (int o = 0; o < CH; ++o) { acc0[o] = 0.0f; acc1[o] = 0.0f; }

  float inv0 = v0 ? 1.0f / fmaxf(degf[node0], 1.0f) : 0.0f;
  float inv1 = v1 ? 1.0f / fmaxf(degf[node1], 1.0f) : 0.0f;
  const float4* S0 = (const float4*)(S + (size_t)node0 * CH);
  const float4* S1 = (const float4*)(S + (size_t)node1 * CH);
  const float4* A0 = (const float4*)(A1 + (size_t)node0 * CH);
  const float4* A1p = (const float4*)(A1 + (size_t)node1 * CH);
  const float4* X0 = (const float4*)(x + (size_t)node0 * CH);
  const float4* X1 = (const float4*)(x + (size_t)node1 * CH);

  accum2(acc0, acc1, S0, S1, inv0, inv1, M, v0, v1);             // (S/deg)@W0
  accum2(acc0, acc1, A0, A1p, inv0, inv1, M + 64 * CH, v0, v1);  // (A1/deg)@(W1-W0)
  accum2(acc0, acc1, X0, X1, 1.0f, 1.0f, M + 128 * CH, v0, v1);  // x@root

  float4* O0 = (float4*)(out + (size_t)node0 * CH);
  float4* O1 = (float4*)(out + (size_t)node1 * CH);
#pragma unroll
  for (int o4 = 0; o4 < 16; ++o4) {
    float4 r;
    r.x = fmaxf(acc0[o4 * 4 + 0] + bs[o4 * 4 + 0], 0.0f);
    r.y = fmaxf(acc0[o4 * 4 + 1] + bs[o4 * 4 + 1], 0.0f);
    r.z = fmaxf(acc0[o4 * 4 + 2] + bs[o4 * 4 + 2], 0.0f);
    r.w = fmaxf(acc0[o4 * 4 + 3] + bs[o4 * 4 + 3], 0.0f);
    O0[o4] = r;
  }
  if (v1) {
#pragma unroll
    for (int o4 = 0; o4 < 16; ++o4) {
      float4 r;
      r.x = fmaxf(acc1[o4 * 4 + 0] + bs[o4 * 4 + 0], 0.0f);
      r.y = fmaxf(acc1[o4 * 4 + 1] + bs[o4 * 4 + 1], 0.0f);
      r.z = fmaxf(acc1[o4 * 4 + 2] + bs[o4 * 4 + 2], 0.0f);
      r.w = fmaxf(acc1[o4 * 4 + 3] + bs[o4 * 4 + 3], 0.0f);
      O1[o4] = r;
    }
  }
}

extern "C" void kernel_launch(void* const* d_in, const int* in_sizes, int n_in,
                              void* d_out, int out_size, void* d_ws, size_t ws_size,
                              hipStream_t stream) {
  const float* x    = (const float*)d_in[0];
  const int*   ei   = (const int*)d_in[1];
  const float* attr = (const float*)d_in[2];
  const float* W    = (const float*)d_in[3];
  const float* root = (const float*)d_in[4];
  const float* bias = (const float*)d_in[5];
  float* out = (float*)d_out;

  int n = in_sizes[0] / CH;   // 100000
  int E = in_sizes[2];        // 1200000

  size_t cntB = (((size_t)n * 4) + 255) & ~(size_t)255;
  size_t bktB = (size_t)n * CAP * 8;
  size_t sB   = (size_t)n * CH * 4;
  size_t degB = (((size_t)n * 4) + 255) & ~(size_t)255;
  size_t need = cntB + bktB + 2 * sB + degB;

  int gemm_blocks = (n + 511) / 512;

  if (ws_size >= need) {
    // main path: counting-sort buckets + gather
    int*   cnt    = (int*)d_ws;
    int2*  bucket = (int2*)((char*)d_ws + cntB);
    float* S      = (float*)((char*)d_ws + cntB + bktB);
    float* A1     = S + (size_t)n * CH;
    float* degf   = (float*)((char*)d_ws + cntB + bktB + 2 * sB);

    hipMemsetAsync(cnt, 0, (size_t)n * 4, stream);
    spline_fill<<<(E + 255) / 256, 256, 0, stream>>>(ei, attr, cnt, bucket, E);
    spline_gather<<<(n + 3) / 4, 256, 0, stream>>>(x, cnt, bucket, S, A1, degf, n);
    spline_gemm2<<<gemm_blocks, 256, 0, stream>>>(S, A1, degf, x, W, root, bias, out, n);
  } else {
    // fallback: R2 atomic scatter
    float* S    = (float*)d_ws;
    float* A1   = S + (size_t)n * CH;
    float* degf = A1 + (size_t)n * CH;
    hipMemsetAsync(d_ws, 0, 2 * sB + (size_t)n * 4, stream);
    spline_scatter<<<(E + 3) / 4, 256, 0, stream>>>(x, ei, attr, S, A1, degf, E);
    spline_gemm2<<<gemm_blocks, 256, 0, stream>>>(S, A1, degf, x, W, root, bias, out, n);
  }
}

// Round 4
// 301.628 us; speedup vs baseline: 9.9626x; 9.9626x over previous
//
#include <hip/hip_runtime.h>
#include <hip/hip_bf16.h>

// SplineConv, K=2 degree-1 B-spline, 1-D pseudo-coords.
// out[n] = relu( mean_{e->n}( (1-v)x_src@W0 + v x_src@W1 ) + x[n]@root + bias )
//   = relu( (S/deg)@W0 + (A1/deg)@(W1-W0) + x@root + bias )
// S[n] = sum_{e->n} x[src_e], A1[n] = sum_{e->n} v_e * x[src_e].
//
// R2: f32-atomic scatter saturated TCC atomic ALU (284G atomics/s, 541us).
// R3: 2-node gemm spilled (VGPR=256, 5.5GB scratch traffic, 2610us). Lesson:
//     gemm with 1 thread/node is occupancy-bound (1563 waves total), and
//     doubling per-thread state spills. R4: 4 threads/node (16 outs each),
//     acc[16], 6250 waves, VGPR capped via __launch_bounds__(512,4).

#define CH 64
#define CAP 64  // bucket capacity; deg ~ Poisson(12), P(deg>64) ~ 1e-23

// ---------- bucket build ----------

__global__ __launch_bounds__(256) void spline_fill(
    const int* __restrict__ ei, const float* __restrict__ attr,
    int* __restrict__ cnt, int2* __restrict__ bucket, int E) {
  int e = blockIdx.x * 256 + threadIdx.x;
  if (e >= E) return;
  int src = ei[e];
  int dst = ei[E + e];
  float v = attr[e];
  int pos = atomicAdd(&cnt[dst], 1);
  if (pos < CAP) bucket[(size_t)dst * CAP + pos] = make_int2(src, __float_as_int(v));
}

__global__ __launch_bounds__(256) void spline_gather(
    const float* __restrict__ x, const int* __restrict__ cnt,
    const int2* __restrict__ bucket, float* __restrict__ S,
    float* __restrict__ A1, float* __restrict__ degf, int n) {
  int node = blockIdx.x * 4 + (threadIdx.x >> 6);
  int lane = threadIdx.x & 63;
  if (node >= n) return;
  int ctrue = cnt[node];
  int c = ctrue > CAP ? CAP : ctrue;
  int2 ent = make_int2(0, 0);
  if (lane < c) ent = bucket[(size_t)node * CAP + lane];
  float s = 0.0f, a = 0.0f;
  for (int j = 0; j < c; ++j) {
    int srcj = __shfl(ent.x, j);
    float vj = __int_as_float(__shfl(ent.y, j));
    float xv = x[(size_t)srcj * CH + lane];  // coalesced 256B gather, L2/L3-resident
    s += xv;
    a = fmaf(vj, xv, a);
  }
  S[(size_t)node * CH + lane] = s;
  A1[(size_t)node * CH + lane] = a;
  if (lane == 0) degf[node] = (float)ctrue;
}

// ---------- fallback scatter (if ws too small) ----------

__global__ __launch_bounds__(256) void spline_scatter(
    const float* __restrict__ x, const int* __restrict__ ei,
    const float* __restrict__ attr, float* __restrict__ S,
    float* __restrict__ A1, float* __restrict__ degf, int E) {
  int w = (int)((blockIdx.x * 4) + (threadIdx.x >> 6));
  int lane = threadIdx.x & 63;
  if (w >= E) return;
  int src = ei[w];
  int dst = ei[E + w];
  float v = attr[w];
  float xv = x[(size_t)src * CH + lane];
  atomicAdd(&S[(size_t)dst * CH + lane], xv);
  atomicAdd(&A1[(size_t)dst * CH + lane], v * xv);
  if (lane == 0) atomicAdd(&degf[dst], 1.0f);
}

// ---------- fused K=192 GEMM: 4 threads/node, 16 outputs each ----------

__device__ __forceinline__ void accum_q(
    float acc[16], const float4* __restrict__ row4, float scale,
    const float* __restrict__ Mseg, int q) {
#pragma unroll 2
  for (int k4 = 0; k4 < 16; ++k4) {
    float4 rv = row4[k4];
    float vals[4] = {rv.x * scale, rv.y * scale, rv.z * scale, rv.w * scale};
#pragma unroll
    for (int j = 0; j < 4; ++j) {
      const float4* Mr = (const float4*)(Mseg + (k4 * 4 + j) * CH + q * 16);
      float s = vals[j];
#pragma unroll
      for (int o4 = 0; o4 < 4; ++o4) {
        float4 m = Mr[o4];  // LDS, 4 distinct 16B addrs/wave -> ~conflict-free
        acc[o4 * 4 + 0] = fmaf(s, m.x, acc[o4 * 4 + 0]);
        acc[o4 * 4 + 1] = fmaf(s, m.y, acc[o4 * 4 + 1]);
        acc[o4 * 4 + 2] = fmaf(s, m.z, acc[o4 * 4 + 2]);
        acc[o4 * 4 + 3] = fmaf(s, m.w, acc[o4 * 4 + 3]);
      }
    }
  }
}

__global__ __launch_bounds__(512, 4) void spline_gemm_q(
    const float* __restrict__ S, const float* __restrict__ A1,
    const float* __restrict__ degf, const float* __restrict__ x,
    const float* __restrict__ W, const float* __restrict__ root,
    const float* __restrict__ bias, float* __restrict__ out, int n) {
  __shared__ float M[192 * CH];  // 0..63: W0; 64..127: W1-W0; 128..191: root
  __shared__ float bs[CH];
  int t = threadIdx.x;
  for (int idx = t; idx < 64 * 64; idx += 512) {
    int i = idx >> 6, o = idx & 63;
    float w0 = W[i * 64 + o];
    float w1 = W[4096 + i * 64 + o];
    M[i * 64 + o] = w0;
    M[(64 + i) * 64 + o] = w1 - w0;
    M[(128 + i) * 64 + o] = root[i * 64 + o];
  }
  if (t < 64) bs[t] = bias[t];
  __syncthreads();

  int node = blockIdx.x * 128 + (t >> 2);  // lanes 0-3 share a node
  int q = t & 3;                           // output quarter
  if (node >= n) return;

  float acc[16];
#pragma unroll
  for (int i = 0; i < 16; ++i) acc[i] = 0.0f;

  float inv = 1.0f / fmaxf(degf[node], 1.0f);
  accum_q(acc, (const float4*)(S + (size_t)node * CH), inv, M, q);
  accum_q(acc, (const float4*)(A1 + (size_t)node * CH), inv, M + 64 * CH, q);
  accum_q(acc, (const float4*)(x + (size_t)node * CH), 1.0f, M + 128 * CH, q);

  float4* O4 = (float4*)(out + (size_t)node * CH + q * 16);
#pragma unroll
  for (int o4 = 0; o4 < 4; ++o4) {
    float4 r;
    r.x = fmaxf(acc[o4 * 4 + 0] + bs[q * 16 + o4 * 4 + 0], 0.0f);
    r.y = fmaxf(acc[o4 * 4 + 1] + bs[q * 16 + o4 * 4 + 1], 0.0f);
    r.z = fmaxf(acc[o4 * 4 + 2] + bs[q * 16 + o4 * 4 + 2], 0.0f);
    r.w = fmaxf(acc[o4 * 4 + 3] + bs[q * 16 + o4 * 4 + 3], 0.0f);
    O4[o4] = r;
  }
}

extern "C" void kernel_launch(void* const* d_in, const int* in_sizes, int n_in,
                              void* d_out, int out_size, void* d_ws, size_t ws_size,
                              hipStream_t stream) {
  const float* x    = (const float*)d_in[0];
  const int*   ei   = (const int*)d_in[1];
  const float* attr = (const float*)d_in[2];
  const float* W    = (const float*)d_in[3];
  const float* root = (const float*)d_in[4];
  const float* bias = (const float*)d_in[5];
  float* out = (float*)d_out;

  int n = in_sizes[0] / CH;   // 100000
  int E = in_sizes[2];        // 1200000

  size_t cntB = (((size_t)n * 4) + 255) & ~(size_t)255;
  size_t bktB = (size_t)n * CAP * 8;
  size_t sB   = (size_t)n * CH * 4;
  size_t degB = (((size_t)n * 4) + 255) & ~(size_t)255;
  size_t need = cntB + bktB + 2 * sB + degB;

  int gemm_blocks = (n + 127) / 128;

  if (ws_size >= need) {
    int*   cnt    = (int*)d_ws;
    int2*  bucket = (int2*)((char*)d_ws + cntB);
    float* S      = (float*)((char*)d_ws + cntB + bktB);
    float* A1     = S + (size_t)n * CH;
    float* degf   = (float*)((char*)d_ws + cntB + bktB + 2 * sB);

    hipMemsetAsync(cnt, 0, (size_t)n * 4, stream);
    spline_fill<<<(E + 255) / 256, 256, 0, stream>>>(ei, attr, cnt, bucket, E);
    spline_gather<<<(n + 3) / 4, 256, 0, stream>>>(x, cnt, bucket, S, A1, degf, n);
    spline_gemm_q<<<gemm_blocks, 512, 0, stream>>>(S, A1, degf, x, W, root, bias, out, n);
  } else {
    float* S    = (float*)d_ws;
    float* A1   = S + (size_t)n * CH;
    float* degf = A1 + (size_t)n * CH;
    hipMemsetAsync(d_ws, 0, 2 * sB + (size_t)n * 4, stream);
    spline_scatter<<<(E + 3) / 4, 256, 0, stream>>>(x, ei, attr, S, A1, degf, E);
    spline_gemm_q<<<gemm_blocks, 512, 0, stream>>>(S, A1, degf, x, W, root, bias, out, n);
  }
}

// Round 5
// 248.996 us; speedup vs baseline: 12.0684x; 1.2114x over previous
//
#include <hip/hip_runtime.h>
#include <hip/hip_bf16.h>

// SplineConv K=2:  out = relu( (S/deg)@W0 + (A1/deg)@(W1-W0) + x@root + bias )
// S[n] = sum_{e->n} x[src_e],  A1[n] = sum_{e->n} v_e x[src_e].
//
// R2: f32-atomic scatter = TCC atomic-ALU bound (541us).
// R3: 2-node f32 gemm spilled (VGPR 256, 5.5GB scratch, 2610us).
// R4: 301us = fill 92 + gather 92 + gemm_q ~90. gemm_q is LDS-read-bound
//     (768 b128/thread, no reuse); gather is serialized-load-latency-bound;
//     fill is random-8B-store line-traffic (74.8MB lines for 9.6MB payload).
// R5: gemm -> bf16 MFMA (B frags in regs, A coalesced from global);
//     gather -> LDS-broadcast entries + 8-deep batched gathers, bf16 x,
//     writes pre-scaled bf16 S/A1. fill unchanged (next target).

#define CH 64
#define CAP 64  // deg ~ Poisson(12); P(deg>64) ~ 1e-23

typedef __attribute__((ext_vector_type(8))) short bf16x8;
typedef __attribute__((ext_vector_type(4))) float f32x4;
typedef __attribute__((ext_vector_type(8))) unsigned short u16x8;

static __device__ __forceinline__ unsigned short f2bu(float f) {
  __hip_bfloat16 h = __float2bfloat16(f);  // RTN
  return *(unsigned short*)&h;
}
static __device__ __forceinline__ float bu2f(unsigned short u) {
  unsigned int w = ((unsigned int)u) << 16;
  return __uint_as_float(w);
}

// ---------- cast x (f32) -> xb (bf16) ----------
__global__ __launch_bounds__(256) void cast_x(
    const float* __restrict__ x, unsigned short* __restrict__ xb, int total) {
  int i = (blockIdx.x * 256 + threadIdx.x) * 8;
  if (i >= total) return;
  const float4* p = (const float4*)(x + i);
  float4 a = p[0], b = p[1];
  u16x8 o;
  o[0] = f2bu(a.x); o[1] = f2bu(a.y); o[2] = f2bu(a.z); o[3] = f2bu(a.w);
  o[4] = f2bu(b.x); o[5] = f2bu(b.y); o[6] = f2bu(b.z); o[7] = f2bu(b.w);
  *(u16x8*)(xb + i) = o;
}

// ---------- bucket build (unchanged) ----------
__global__ __launch_bounds__(256) void spline_fill(
    const int* __restrict__ ei, const float* __restrict__ attr,
    int* __restrict__ cnt, int2* __restrict__ bucket, int E) {
  int e = blockIdx.x * 256 + threadIdx.x;
  if (e >= E) return;
  int src = ei[e];
  int dst = ei[E + e];
  float v = attr[e];
  int pos = atomicAdd(&cnt[dst], 1);
  if (pos < CAP) bucket[(size_t)dst * CAP + pos] = make_int2(src, __float_as_int(v));
}

// ---------- gather: LDS-broadcast entries, 8-deep batched gathers ----------
__global__ __launch_bounds__(256) void spline_gather(
    const unsigned short* __restrict__ xb, const int* __restrict__ cnt,
    const int2* __restrict__ bucket, unsigned short* __restrict__ Sb,
    unsigned short* __restrict__ Ab, int n) {
  __shared__ int2 entlds[4 * (CAP + 8)];
  int wv = threadIdx.x >> 6;
  int lane = threadIdx.x & 63;
  int node = blockIdx.x * 4 + wv;
  if (node >= n) return;
  int wbase = wv * (CAP + 8);
  int ctrue = cnt[node];
  int c = ctrue > CAP ? CAP : ctrue;
  // stage entries; slots >= c are zero (v=0 kills their contribution to a)
  entlds[wbase + lane] = (lane < c) ? bucket[(size_t)node * CAP + lane]
                                    : make_int2(0, 0);
  if (lane < 8) entlds[wbase + CAP + lane] = make_int2(0, 0);
  asm volatile("s_waitcnt lgkmcnt(0)" ::: "memory");  // wave-private LDS ready

  float s = 0.0f, a = 0.0f;
  for (int j = 0; j < c; j += 8) {
    float xv[8], vv[8], w[8];
#pragma unroll
    for (int u = 0; u < 8; ++u) {
      int jj = j + u;
      int2 e = entlds[wbase + jj];                 // broadcast ds_read_b64
      xv[u] = bu2f(xb[(size_t)e.x * CH + lane]);   // independent gathers
      vv[u] = __int_as_float(e.y);
      w[u] = (jj < c) ? 1.0f : 0.0f;               // wave-uniform
    }
#pragma unroll
    for (int u = 0; u < 8; ++u) {
      s = fmaf(w[u], xv[u], s);
      a = fmaf(vv[u], xv[u], a);                   // pad slots have vv=0
    }
  }
  float inv = 1.0f / fmaxf((float)ctrue, 1.0f);    // fold mean into S,A1
  Sb[(size_t)node * CH + lane] = f2bu(s * inv);
  Ab[(size_t)node * CH + lane] = f2bu(a * inv);
}

// ---------- fallback scatter (ws too small) ----------
__global__ __launch_bounds__(256) void spline_scatter(
    const float* __restrict__ x, const int* __restrict__ ei,
    const float* __restrict__ attr, float* __restrict__ S,
    float* __restrict__ A1, float* __restrict__ degf, int E) {
  int w = (int)((blockIdx.x * 4) + (threadIdx.x >> 6));
  int lane = threadIdx.x & 63;
  if (w >= E) return;
  int src = ei[w];
  int dst = ei[E + w];
  float v = attr[w];
  float xv = x[(size_t)src * CH + lane];
  atomicAdd(&S[(size_t)dst * CH + lane], xv);
  atomicAdd(&A1[(size_t)dst * CH + lane], v * xv);
  if (lane == 0) atomicAdd(&degf[dst], 1.0f);
}

__global__ __launch_bounds__(256) void conv_fb(
    const float* __restrict__ S, const float* __restrict__ A1,
    const float* __restrict__ degf, unsigned short* __restrict__ Sb,
    unsigned short* __restrict__ Ab, int total) {
  int i = blockIdx.x * 256 + threadIdx.x;
  if (i >= total) return;
  float inv = 1.0f / fmaxf(degf[i >> 6], 1.0f);
  Sb[i] = f2bu(S[i] * inv);
  Ab[i] = f2bu(A1[i] * inv);
}

// ---------- bf16 MFMA GEMM: [n,192] x [192,64], K folded as 3 segments ----------
__global__ __launch_bounds__(256) void spline_gemm_mfma(
    const unsigned short* __restrict__ Sb, const unsigned short* __restrict__ Ab,
    const unsigned short* __restrict__ Xb, const float* __restrict__ W,
    const float* __restrict__ root, const float* __restrict__ bias,
    float* __restrict__ out, int n, int ntiles) {
  __shared__ unsigned short Mt[64][200];  // M^T[out][k], pad 192->200 (2-way banks)
  int t = threadIdx.x;
  for (int idx = t; idx < 192 * 64; idx += 256) {
    int k = idx >> 6, o = idx & 63;  // coalesced reads of W rows
    float val;
    if (k < 64)       val = W[k * 64 + o];
    else if (k < 128) val = W[4096 + (k - 64) * 64 + o] - W[(k - 64) * 64 + o];
    else              val = root[(k - 128) * 64 + o];
    Mt[o][k] = f2bu(val);
  }
  __syncthreads();

  int tile = blockIdx.x * 4 + (t >> 6);
  if (tile >= ntiles) return;
  int lane = t & 63;
  int nb = tile * 16;
  int arow = nb + (lane & 15);
  if (arow >= n) arow = n - 1;     // clamp: duplicate row, stores guarded
  int kq = (lane >> 4) * 8;

  f32x4 acc[4] = {f32x4{0,0,0,0}, f32x4{0,0,0,0}, f32x4{0,0,0,0}, f32x4{0,0,0,0}};
  const unsigned short* seg0 = Sb;
  const unsigned short* seg1 = Ab;
  const unsigned short* seg2 = Xb;
#pragma unroll
  for (int ks = 0; ks < 6; ++ks) {
    const unsigned short* base = (ks < 2) ? seg0 : (ks < 4) ? seg1 : seg2;
    bf16x8 afrag = *(const bf16x8*)(base + (size_t)arow * CH + (ks & 1) * 32 + kq);
#pragma unroll
    for (int nc = 0; nc < 4; ++nc) {
      bf16x8 bfrag = *(const bf16x8*)(&Mt[nc * 16 + (lane & 15)][ks * 32 + kq]);
      acc[nc] = __builtin_amdgcn_mfma_f32_16x16x32_bf16(afrag, bfrag, acc[nc], 0, 0, 0);
    }
  }

  // C/D: col = lane&15, row = (lane>>4)*4 + reg  [m89-verified]
  int col0 = lane & 15;
  int rbase = (lane >> 4) * 4;
#pragma unroll
  for (int nc = 0; nc < 4; ++nc) {
    float bv = bias[nc * 16 + col0];
#pragma unroll
    for (int r = 0; r < 4; ++r) {
      int node = nb + rbase + r;
      if (node < n)
        out[(size_t)node * CH + nc * 16 + col0] = fmaxf(acc[nc][r] + bv, 0.0f);
    }
  }
}

extern "C" void kernel_launch(void* const* d_in, const int* in_sizes, int n_in,
                              void* d_out, int out_size, void* d_ws, size_t ws_size,
                              hipStream_t stream) {
  const float* x    = (const float*)d_in[0];
  const int*   ei   = (const int*)d_in[1];
  const float* attr = (const float*)d_in[2];
  const float* W    = (const float*)d_in[3];
  const float* root = (const float*)d_in[4];
  const float* bias = (const float*)d_in[5];
  float* out = (float*)d_out;

  int n = in_sizes[0] / CH;   // 100000
  int E = in_sizes[2];        // 1200000
  int total = n * CH;
  int ntiles = (n + 15) / 16;

  size_t cntB = (((size_t)n * 4) + 255) & ~(size_t)255;
  size_t bktB = (size_t)n * CAP * 8;
  size_t sbB  = (size_t)n * CH * 2;
  size_t need_main = cntB + bktB + 3 * sbB;

  if (ws_size >= need_main) {
    int*   cnt    = (int*)d_ws;
    int2*  bucket = (int2*)((char*)d_ws + cntB);
    unsigned short* Sb = (unsigned short*)((char*)d_ws + cntB + bktB);
    unsigned short* Ab = Sb + (size_t)n * CH;
    unsigned short* xb = Ab + (size_t)n * CH;

    cast_x<<<(total / 8 + 255) / 256, 256, 0, stream>>>(x, xb, total);
    hipMemsetAsync(cnt, 0, (size_t)n * 4, stream);
    spline_fill<<<(E + 255) / 256, 256, 0, stream>>>(ei, attr, cnt, bucket, E);
    spline_gather<<<(n + 3) / 4, 256, 0, stream>>>(xb, cnt, bucket, Sb, Ab, n);
    spline_gemm_mfma<<<(ntiles + 3) / 4, 256, 0, stream>>>(Sb, Ab, xb, W, root,
                                                           bias, out, n, ntiles);
  } else {
    size_t fS = (size_t)n * CH * 4;
    float* S    = (float*)d_ws;
    float* A1   = S + (size_t)n * CH;
    float* degf = A1 + (size_t)n * CH;
    unsigned short* Sb = (unsigned short*)((char*)degf + cntB);
    unsigned short* Ab = Sb + (size_t)n * CH;
    unsigned short* xb = Ab + (size_t)n * CH;

    cast_x<<<(total / 8 + 255) / 256, 256, 0, stream>>>(x, xb, total);
    hipMemsetAsync(d_ws, 0, 2 * fS + (size_t)n * 4, stream);
    spline_scatter<<<(E + 3) / 4, 256, 0, stream>>>(x, ei, attr, S, A1, degf, E);
    conv_fb<<<(total + 255) / 256, 256, 0, stream>>>(S, A1, degf, Sb, Ab, total);
    spline_gemm_mfma<<<(ntiles + 3) / 4, 256, 0, stream>>>(Sb, Ab, xb, W, root,
                                                           bias, out, n, ntiles);
  }
}

// Round 7
// 244.137 us; speedup vs baseline: 12.3086x; 1.0199x over previous
//
#include <hip/hip_runtime.h>
#include <hip/hip_bf16.h>

// SplineConv K=2:  out = relu( (S/deg)@W0 + (A1/deg)@(W1-W0) + x@root + bias )
// S[n] = sum_{e->n} x[src_e],  A1[n] = sum_{e->n} v_e x[src_e].
//
// R2: f32-atomic scatter = TCC atomic-ALU bound (541us).
// R3: 2-node f32 gemm spilled (VGPR 256, 2610us).
// R4: 301us = fill 92 + gather 92 + gemm_q ~90 (LDS-read-bound).
// R5: 249us; fill 88us top (WRITE 74.7MB for 9.6MB payload: 8B-store lines).
// R6: FAILED absmax 0.25 — fill's 2-edge unroll had no i<half guard; 64
//     edges double-inserted. Fix: early return. Design otherwise unchanged:
//     4B packed entries (src<<15|v15), 16-deep gather, reg-B-frag MFMA gemm.

#define CH 64
#define CAP 64  // deg ~ Poisson(12); P(deg>64) ~ 1e-23

typedef __attribute__((ext_vector_type(8))) short bf16x8;
typedef __attribute__((ext_vector_type(4))) float f32x4;
typedef __attribute__((ext_vector_type(8))) unsigned short u16x8;

static __device__ __forceinline__ unsigned short f2bu(float f) {
  __hip_bfloat16 h = __float2bfloat16(f);  // RTN
  return *(unsigned short*)&h;
}
static __device__ __forceinline__ float bu2f(unsigned short u) {
  return __uint_as_float(((unsigned)u) << 16);
}

// ---------- combined weight M^T bf16 [64][192] ----------
// k 0..63: W0 ; 64..127: W1-W0 ; 128..191: root
__global__ __launch_bounds__(256) void build_M(
    const float* __restrict__ W, const float* __restrict__ root,
    unsigned short* __restrict__ Mb) {
  int idx = blockIdx.x * 256 + threadIdx.x;
  if (idx >= 192 * 64) return;
  int k = idx >> 6, o = idx & 63;
  float val;
  if (k < 64)       val = W[k * 64 + o];
  else if (k < 128) val = W[4096 + (k - 64) * 64 + o] - W[(k - 64) * 64 + o];
  else              val = root[(k - 128) * 64 + o];
  Mb[o * 192 + k] = f2bu(val);
}

// ---------- cast x (f32) -> xb (bf16) ----------
__global__ __launch_bounds__(256) void cast_x(
    const float* __restrict__ x, unsigned short* __restrict__ xb, int total) {
  int i = (blockIdx.x * 256 + threadIdx.x) * 8;
  if (i >= total) return;
  const float4* p = (const float4*)(x + i);
  float4 a = p[0], b = p[1];
  u16x8 o;
  o[0] = f2bu(a.x); o[1] = f2bu(a.y); o[2] = f2bu(a.z); o[3] = f2bu(a.w);
  o[4] = f2bu(b.x); o[5] = f2bu(b.y); o[6] = f2bu(b.z); o[7] = f2bu(b.w);
  *(u16x8*)(xb + i) = o;
}

// ---------- bucket build: 4B packed entries, 2 edges/thread ----------
__global__ __launch_bounds__(256) void spline_fill(
    const int* __restrict__ ei, const float* __restrict__ attr,
    int* __restrict__ cnt, unsigned* __restrict__ bucket, int E, int half) {
  int i = blockIdx.x * 256 + threadIdx.x;
  if (i >= half) return;  // R6 bug fix: tail threads must not process p=0
#pragma unroll
  for (int p = 0; p < 2; ++p) {
    int e = i + p * half;
    if (e < E) {
      int src = ei[e];
      int dst = ei[E + e];
      float v = attr[e];
      unsigned enc = ((unsigned)src << 15) | (unsigned)(v * 32767.0f + 0.5f);
      int pos = atomicAdd(&cnt[dst], 1);
      if (pos < CAP) bucket[(size_t)dst * CAP + pos] = enc;
    }
  }
}

// ---------- gather: parallel issue, 16-deep batched gathers ----------
__global__ __launch_bounds__(256) void spline_gather(
    const unsigned short* __restrict__ xb, const int* __restrict__ cnt,
    const unsigned* __restrict__ bucket, unsigned short* __restrict__ Sb,
    unsigned short* __restrict__ Ab, int n) {
  int node = blockIdx.x * 4 + (threadIdx.x >> 6);
  int lane = threadIdx.x & 63;
  if (node >= n) return;
  int ctrue = cnt[node];                              // load A (issues now)
  unsigned ent = bucket[(size_t)node * CAP + lane];   // load B (parallel, unmasked)
  int c = ctrue > CAP ? CAP : ctrue;
  float s = 0.0f, a = 0.0f;
  for (int j = 0; j < c; j += 16) {
    unsigned short xr[16];
    unsigned ee[16];
#pragma unroll
    for (int u = 0; u < 16; ++u) {
      int jj = j + u;                      // <= 63 always (j mult of 16 < c <= 64)
      unsigned e = __shfl(ent, jj);        // broadcast entry of lane jj
      bool val = jj < c;                   // wave-uniform
      ee[u] = val ? e : 0u;                // invalid -> vq = 0
      int srcj = val ? (int)(e >> 15) : 0; // clamp poison src (OOB guard)
      xr[u] = xb[(size_t)srcj * CH + lane];  // 16 independent 128B gathers
    }
#pragma unroll
    for (int u = 0; u < 16; ++u) {
      float w = (j + u < c) ? 1.0f : 0.0f;
      float xv = bu2f(xr[u]);
      float vv = (float)(ee[u] & 32767u) * (1.0f / 32767.0f);
      s = fmaf(w, xv, s);
      a = fmaf(w * vv, xv, a);
    }
  }
  float inv = 1.0f / fmaxf((float)ctrue, 1.0f);  // fold mean into S,A1
  Sb[(size_t)node * CH + lane] = f2bu(s * inv);
  Ab[(size_t)node * CH + lane] = f2bu(a * inv);
}

// ---------- fallback scatter path (ws too small) ----------
__global__ __launch_bounds__(256) void spline_scatter(
    const float* __restrict__ x, const int* __restrict__ ei,
    const float* __restrict__ attr, float* __restrict__ S,
    float* __restrict__ A1, float* __restrict__ degf, int E) {
  int w = (int)((blockIdx.x * 4) + (threadIdx.x >> 6));
  int lane = threadIdx.x & 63;
  if (w >= E) return;
  int src = ei[w];
  int dst = ei[E + w];
  float v = attr[w];
  float xv = x[(size_t)src * CH + lane];
  atomicAdd(&S[(size_t)dst * CH + lane], xv);
  atomicAdd(&A1[(size_t)dst * CH + lane], v * xv);
  if (lane == 0) atomicAdd(&degf[dst], 1.0f);
}

__global__ __launch_bounds__(256) void conv_fb(
    const float* __restrict__ S, const float* __restrict__ A1,
    const float* __restrict__ degf, unsigned short* __restrict__ Sb,
    unsigned short* __restrict__ Ab, int total) {
  int i = blockIdx.x * 256 + threadIdx.x;
  if (i >= total) return;
  float inv = 1.0f / fmaxf(degf[i >> 6], 1.0f);
  Sb[i] = f2bu(S[i] * inv);
  Ab[i] = f2bu(A1[i] * inv);
}

// ---------- MFMA GEMM: B-frags in regs, 2 tiles/wave, no LDS ----------
__global__ __launch_bounds__(256) void spline_gemm_mfma(
    const unsigned short* __restrict__ Sb, const unsigned short* __restrict__ Ab,
    const unsigned short* __restrict__ Xb, const unsigned short* __restrict__ Mb,
    const float* __restrict__ bias, float* __restrict__ out, int n, int ntiles) {
  int t = threadIdx.x;
  int lane = t & 63;
  int col = lane & 15;
  int kq = (lane >> 4) * 8;

  bf16x8 bfrag[6][4];  // 96 VGPRs, loaded once, L2-hot
#pragma unroll
  for (int ks = 0; ks < 6; ++ks)
#pragma unroll
    for (int nc = 0; nc < 4; ++nc)
      bfrag[ks][nc] = *(const bf16x8*)(Mb + (nc * 16 + col) * 192 + ks * 32 + kq);

  float bv[4];
#pragma unroll
  for (int nc = 0; nc < 4; ++nc) bv[nc] = bias[nc * 16 + col];

  int tbase = blockIdx.x * 8 + (t >> 6) * 2;
#pragma unroll
  for (int tt = 0; tt < 2; ++tt) {
    int tile = tbase + tt;
    if (tile >= ntiles) continue;
    int nb = tile * 16;
    int arow = nb + col;
    if (arow >= n) arow = n - 1;  // clamp (stores guarded)

    f32x4 acc[4] = {f32x4{0,0,0,0}, f32x4{0,0,0,0}, f32x4{0,0,0,0}, f32x4{0,0,0,0}};
#pragma unroll
    for (int ks = 0; ks < 6; ++ks) {
      const unsigned short* base = (ks < 2) ? Sb : (ks < 4) ? Ab : Xb;
      bf16x8 afrag = *(const bf16x8*)(base + (size_t)arow * CH + (ks & 1) * 32 + kq);
#pragma unroll
      for (int nc = 0; nc < 4; ++nc)
        acc[nc] = __builtin_amdgcn_mfma_f32_16x16x32_bf16(afrag, bfrag[ks][nc],
                                                          acc[nc], 0, 0, 0);
    }
    // C/D: col = lane&15, row = (lane>>4)*4 + reg  [m89-verified]
    int rbase = (lane >> 4) * 4;
#pragma unroll
    for (int nc = 0; nc < 4; ++nc) {
#pragma unroll
      for (int r = 0; r < 4; ++r) {
        int node = nb + rbase + r;
        if (node < n)
          out[(size_t)node * CH + nc * 16 + col] = fmaxf(acc[nc][r] + bv[nc], 0.0f);
      }
    }
  }
}

extern "C" void kernel_launch(void* const* d_in, const int* in_sizes, int n_in,
                              void* d_out, int out_size, void* d_ws, size_t ws_size,
                              hipStream_t stream) {
  const float* x    = (const float*)d_in[0];
  const int*   ei   = (const int*)d_in[1];
  const float* attr = (const float*)d_in[2];
  const float* W    = (const float*)d_in[3];
  const float* root = (const float*)d_in[4];
  const float* bias = (const float*)d_in[5];
  float* out = (float*)d_out;

  int n = in_sizes[0] / CH;   // 100000
  int E = in_sizes[2];        // 1200000
  int total = n * CH;
  int ntiles = (n + 15) / 16;
  int gemm_blocks = (ntiles + 7) / 8;

  size_t MbB  = ((192 * 64 * 2) + 255) & ~(size_t)255;   // 24.6KB
  size_t cntB = (((size_t)n * 4) + 255) & ~(size_t)255;
  size_t bktB = (size_t)n * CAP * 4;                     // 25.6MB (4B entries)
  size_t sbB  = (size_t)n * CH * 2;                      // 12.8MB each
  size_t need_main = MbB + cntB + bktB + 3 * sbB;

  if (ws_size >= need_main) {
    unsigned short* Mb = (unsigned short*)d_ws;
    int*      cnt    = (int*)((char*)d_ws + MbB);
    unsigned* bucket = (unsigned*)((char*)d_ws + MbB + cntB);
    unsigned short* Sb = (unsigned short*)((char*)d_ws + MbB + cntB + bktB);
    unsigned short* Ab = Sb + (size_t)n * CH;
    unsigned short* xb = Ab + (size_t)n * CH;

    build_M<<<48, 256, 0, stream>>>(W, root, Mb);
    cast_x<<<(total / 8 + 255) / 256, 256, 0, stream>>>(x, xb, total);
    hipMemsetAsync(cnt, 0, (size_t)n * 4, stream);
    int half = (E + 1) >> 1;
    spline_fill<<<(half + 255) / 256, 256, 0, stream>>>(ei, attr, cnt, bucket, E, half);
    spline_gather<<<(n + 3) / 4, 256, 0, stream>>>(xb, cnt, bucket, Sb, Ab, n);
    spline_gemm_mfma<<<gemm_blocks, 256, 0, stream>>>(Sb, Ab, xb, Mb, bias, out,
                                                      n, ntiles);
  } else {
    size_t fS = (size_t)n * CH * 4;
    unsigned short* Mb = (unsigned short*)d_ws;
    float* S    = (float*)((char*)d_ws + MbB);
    float* A1   = S + (size_t)n * CH;
    float* degf = A1 + (size_t)n * CH;
    unsigned short* Sb = (unsigned short*)((char*)(degf + n) + 256);
    unsigned short* Ab = Sb + (size_t)n * CH;
    unsigned short* xb = Ab + (size_t)n * CH;

    build_M<<<48, 256, 0, stream>>>(W, root, Mb);
    cast_x<<<(total / 8 + 255) / 256, 256, 0, stream>>>(x, xb, total);
    hipMemsetAsync(S, 0, 2 * fS + (size_t)n * 4, stream);
    spline_scatter<<<(E + 3) / 4, 256, 0, stream>>>(x, ei, attr, S, A1, degf, E);
    conv_fb<<<(total + 255) / 256, 256, 0, stream>>>(S, A1, degf, Sb, Ab, total);
    spline_gemm_mfma<<<gemm_blocks, 256, 0, stream>>>(Sb, Ab, xb, Mb, bias, out,
                                                      n, ntiles);
  }
}